// Round 14
// baseline (251.347 us; speedup 1.0000x reference)
//
#include <hip/hip_runtime.h>

typedef __bf16 bf16;
typedef unsigned short u16;
typedef unsigned int u32;
typedef __attribute__((ext_vector_type(8))) __bf16 bf16x8;
typedef __attribute__((ext_vector_type(4))) __bf16 bf16x4;
typedef __attribute__((ext_vector_type(4))) float f32x4;
typedef __attribute__((ext_vector_type(8))) float f32x8;

// slot index (16B units) for 8-seg rows (64 bf16/row), XOR-swizzled
#define SWZ(r, s) (((r) << 3) + ((s) ^ ((r) & 7)))
// slot index for 4-seg rows (32 bf16/row), XOR-swizzled
#define GSW(r, s) (((r) << 2) + ((s) ^ (((r) >> 1) & 3)))

__device__ __forceinline__ f32x4 mfma16(bf16x8 a, bf16x8 b, f32x4 c) {
  return __builtin_amdgcn_mfma_f32_16x16x32_bf16(a, b, c, 0, 0, 0);
}
__device__ __forceinline__ void gld16(const void* g, void* l) {
  __builtin_amdgcn_global_load_lds((const __attribute__((address_space(1))) void*)g,
                                   (__attribute__((address_space(3))) void*)l, 16, 0, 0);
}

// ---------------------------------------------------------------------------
// prep_all: kT transpose (blocks [0,1280)) + seg_mat->bf16 (blocks [1280,5376))
// ---------------------------------------------------------------------------
__global__ __launch_bounds__(256) void prep_all(
    const float* __restrict__ K, const float* __restrict__ seg_mat,
    bf16* __restrict__ KT, bf16* __restrict__ seg_b) {
  __shared__ float t[64][68];
  const int bid = blockIdx.x, tid = threadIdx.x;
  if (bid < 1280) {
    const int n0 = (bid % 80) << 6, k0 = (bid / 80) << 6;
    for (int idx = tid; idx < 1024; idx += 256) {
      int rr = idx >> 4, c4 = (idx & 15) << 2;
      f32x4 v = *reinterpret_cast<const f32x4*>(K + (size_t)(k0 + rr) * 5120 + n0 + c4);
      t[rr][c4] = v.x; t[rr][c4 + 1] = v.y; t[rr][c4 + 2] = v.z; t[rr][c4 + 3] = v.w;
    }
    __syncthreads();
    for (int idx = tid; idx < 1024; idx += 256) {
      int rr = idx >> 4, c4 = (idx & 15) << 2;
      bf16x4 o = { (bf16)t[c4][rr], (bf16)t[c4 + 1][rr], (bf16)t[c4 + 2][rr], (bf16)t[c4 + 3][rr] };
      *reinterpret_cast<bf16x4*>(KT + (size_t)(n0 + rr) * 1024 + k0 + c4) = o;
    }
  } else {
    size_t i = ((size_t)(bid - 1280) * 256 + tid) * 8;
    f32x8 v = *reinterpret_cast<const f32x8*>(seg_mat + i);
    *reinterpret_cast<bf16x8*>(seg_b + i) = __builtin_convertvector(v, bf16x8);
  }
}

// ---------------------------------------------------------------------------
// GEMM with f32 A-source, converted to bf16 during staging (reg->cvt->LDS).
// AMODE 0: A1 + row*1024. AMODE 1: full (mem/cont split). AMODE 2: clamp 4097.
// Output bf16; col < splitN -> C0 else C1.
// ---------------------------------------------------------------------------
template<int MT, int AMODE>
__device__ __forceinline__ void gemm_f32a(
    const float* __restrict__ A1, const float* __restrict__ A2,
    const bf16* __restrict__ BT, bf16* __restrict__ C0, bf16* __restrict__ C1,
    int m0, int n0, int Mrows, int splitN, bf16* As, bf16* Bs, int tid) {
  const int l = tid & 63, w = tid >> 6;
  const int wn = (w & 1) << 6;
  const int wm = (w >> 1) * (MT / 2);
  constexpr int MFR = MT / 32;
  const int lc = l & 15, l16 = l >> 4;
  f32x4 acc[MFR][4] = {};
  const int r0 = tid >> 2;
  const int sq = tid & 3;
  const int g0 = (sq ^ ((r0 >> 1) & 3)) << 3;   // B pre-swizzled global seg

  auto arow = [&](int row) -> const float* {
    if (AMODE == 0) return A1 + ((size_t)row << 10);
    if (AMODE == 1) {
      int b = row >> 11, rr = row & 2047;
      return (rr < 1024) ? (A1 + (((size_t)(b << 10) + rr) << 10))
                         : (A2 + (((size_t)(b << 10) + (rr - 1024)) << 10));
    }
    int rr = row > 4097 ? 4097 : row;           // relatives has exactly 4098 rows
    return A1 + ((size_t)rr << 10);
  };
  const float* ap0 = arow(m0 + r0);
  const float* ap1 = (MT == 128) ? arow(m0 + r0 + 64) : nullptr;
  // LDS slot (bf16 elems) matching the GSW read: slot r*4+(s^((r>>1)&3)) holds seg s
  const int aslot0 = ((r0 << 2) + (sq ^ ((r0 >> 1) & 3))) << 3;
  const int aslot1 = (((r0 + 64) << 2) + (sq ^ ((r0 >> 1) & 3))) << 3;

  for (int k0 = 0; k0 < 1024; k0 += 32) {
    // issue f32 A loads early (hidden under previous MFMA phase)
    f32x8 a0 = *reinterpret_cast<const f32x8*>(ap0 + k0 + (sq << 3));
    f32x8 a1v = {};
    if (MT == 128) a1v = *reinterpret_cast<const f32x8*>(ap1 + k0 + (sq << 3));
    __syncthreads();   // (a) previous tile consumed
    *reinterpret_cast<bf16x8*>(&As[aslot0]) = __builtin_convertvector(a0, bf16x8);
    if (MT == 128)
      *reinterpret_cast<bf16x8*>(&As[aslot1]) = __builtin_convertvector(a1v, bf16x8);
    gld16(BT + (size_t)(n0 + r0) * 1024 + k0 + g0, &Bs[tid << 3]);
    gld16(BT + (size_t)(n0 + r0 + 64) * 1024 + k0 + g0, &Bs[(tid + 256) << 3]);
    __syncthreads();   // (b) tile ready
    bf16x8 af[MFR], bfv[4];
#pragma unroll
    for (int m = 0; m < MFR; ++m)
      af[m] = *reinterpret_cast<const bf16x8*>(&As[GSW(wm + (m << 4) + lc, l16) << 3]);
#pragma unroll
    for (int n = 0; n < 4; ++n)
      bfv[n] = *reinterpret_cast<const bf16x8*>(&Bs[GSW(wn + (n << 4) + lc, l16) << 3]);
#pragma unroll
    for (int m = 0; m < MFR; ++m)
#pragma unroll
      for (int n = 0; n < 4; ++n)
        acc[m][n] = mfma16(af[m], bfv[n], acc[m][n]);
  }
#pragma unroll
  for (int m = 0; m < MFR; ++m) {
    const int rbase = m0 + wm + (m << 4) + (l16 << 2);
#pragma unroll
    for (int n = 0; n < 4; ++n) {
      const int col = n0 + wn + (n << 4) + lc;
      const int cc = (col < splitN) ? col : (col - splitN);
      bf16* Cv = (col < splitN) ? C0 : C1;
#pragma unroll
      for (int r = 0; r < 4; ++r) {
        const int row = rbase + r;
        if (row < Mrows) Cv[((size_t)row << 10) + cc] = (bf16)acc[m][n][r];
      }
    }
  }
}

// all three projection GEMMs in one launch (904 blocks, all 128x128 tiles)
__global__ __launch_bounds__(256) void proj_fused(
    const float* __restrict__ inputs, const float* __restrict__ mem,
    const float* __restrict__ cont, const float* __restrict__ rel,
    const bf16* __restrict__ kT, bf16* __restrict__ w_q, bf16* __restrict__ w_k,
    bf16* __restrict__ w_v, bf16* __restrict__ w_rh) {
  __shared__ bf16 As[4096];
  __shared__ bf16 Bs[4096];
  const int bid = blockIdx.x, tid = threadIdx.x;
  if (bid < 128) {          // w_q: 16m(128) x 8n
    gemm_f32a<128, 0>(inputs, nullptr, kT, w_q, w_q,
                      (bid >> 3) << 7, (bid & 7) << 7, 2048, 1 << 30, As, Bs, tid);
  } else if (bid < 640) {   // w_kv: 32m(128) x 16n
    const int r = bid - 128;
    gemm_f32a<128, 1>(mem, cont, kT + (1 << 20), w_k, w_v,
                      (r >> 4) << 7, (r & 15) << 7, 4096, 1024, As, Bs, tid);
  } else {                  // w_r: 33m(128) x 8n
    const int r = bid - 640;
    gemm_f32a<128, 2>(rel, nullptr, kT + 3 * (1 << 20), w_rh, w_rh,
                      (r >> 3) << 7, (r & 7) << 7, 4098, 1 << 30, As, Bs, tid);
  }
}

// ---------------------------------------------------------------------------
// out_proj: bf16-A GEMM (a_cat hi|lo, K=2048 with B k-wrap), f32 out
// ---------------------------------------------------------------------------
__global__ __launch_bounds__(256) void out_proj(
    const bf16* __restrict__ a_cat, const bf16* __restrict__ kTo,
    float* __restrict__ out) {
  __shared__ bf16 As[4096];
  __shared__ bf16 Bs[4096];
  const int bid = blockIdx.x, tid = threadIdx.x;
  const int m0 = (bid >> 3) << 6, n0 = (bid & 7) << 7;
  const int l = tid & 63, w = tid >> 6;
  const int wn = (w & 1) << 6;
  const int wm = (w >> 1) << 5;
  const int lc = l & 15, l16 = l >> 4;
  f32x4 acc[2][4] = {};
  const int r0 = tid >> 2;
  const int sq = tid & 3;
  const int g0 = (sq ^ ((r0 >> 1) & 3)) << 3;

  for (int k0 = 0; k0 < 2048; k0 += 32) {
    const int kk = k0 & 1023;
    __syncthreads();
    gld16(a_cat + (size_t)(m0 + r0) * 2048 + k0 + g0, &As[tid << 3]);
    gld16(kTo + (size_t)(n0 + r0) * 1024 + kk + g0, &Bs[tid << 3]);
    gld16(kTo + (size_t)(n0 + r0 + 64) * 1024 + kk + g0, &Bs[(tid + 256) << 3]);
    __syncthreads();
    bf16x8 af[2], bfv[4];
#pragma unroll
    for (int m = 0; m < 2; ++m)
      af[m] = *reinterpret_cast<const bf16x8*>(&As[GSW(wm + (m << 4) + lc, l16) << 3]);
#pragma unroll
    for (int n = 0; n < 4; ++n)
      bfv[n] = *reinterpret_cast<const bf16x8*>(&Bs[GSW(wn + (n << 4) + lc, l16) << 3]);
#pragma unroll
    for (int m = 0; m < 2; ++m)
#pragma unroll
      for (int n = 0; n < 4; ++n)
        acc[m][n] = mfma16(af[m], bfv[n], acc[m][n]);
  }
#pragma unroll
  for (int m = 0; m < 2; ++m) {
    const int rbase = m0 + wm + (m << 4) + (l16 << 2);
#pragma unroll
    for (int n = 0; n < 4; ++n) {
      const int col = n0 + wn + (n << 4) + lc;
#pragma unroll
      for (int r = 0; r < 4; ++r)
        out[((size_t)(rbase + r) << 10) + col] = acc[m][n][r];
    }
  }
}

// ---------------------------------------------------------------------------
// fused attention: round-12 proven structure (frozen). qs in prologue.
// NO setprio, NO defer branch.
// rel shift: diff=j_g-i_g; diff<=1024 -> q_r[i].w_r[diff+1024]
//            diff>=1025 -> q_r[i+1].w_r[diff-1025]
// ---------------------------------------------------------------------------
__global__ __launch_bounds__(256) void attn_mfma(
    const bf16* __restrict__ w_q, const bf16* __restrict__ w_k,
    const bf16* __restrict__ w_v, const bf16* __restrict__ w_rh,
    const bf16* __restrict__ seg_b, const float* __restrict__ perm,
    const float* __restrict__ bias_c, const float* __restrict__ bias_r,
    const float* __restrict__ bias_s, const float* __restrict__ seg_embed,
    bf16* __restrict__ a_cat) {
  const int id = blockIdx.x;
  const int h  = (id >> 3) & 15;
  const int cg = (id & 7) | ((id >> 7) << 3);
  const int qt = cg & 15, b = cg >> 4;
  const int qi0 = qt << 6;
  const int tid = threadIdx.x;
  const int w = tid >> 6, l = tid & 63;
  const int lc = l & 15, l16 = l >> 4;
  const int w16 = w << 4;
  const int myq = w16 + lc;

  __shared__ bf16 kt[2][2048];
  __shared__ u16  vt[2][2560];
  __shared__ bf16 wbc[8192];
  __shared__ bf16 wb2[6144];      // w_r rows 0..95
  __shared__ u16  pl[2560];
  __shared__ float ART[4 * 960];
  __shared__ float facw[64], lroww[64];

  auto stageK = [&](int buf, int kj) {
    int r = tid >> 3, s = tid & 7;
    gld16(w_k + ((size_t)((b << 11) + kj + r) << 10) + (h << 6) + ((s ^ (r & 7)) << 3),
          &kt[buf][tid << 3]);
  };
  auto stageWB = [&](int L0, int nrows, int OFF) {
    for (int base = 0; base < nrows; base += 32) {
      int r = (tid >> 3) + base, s = tid & 7;
      int L = L0 + r;
      int slot = (L + OFF) & 127;
      int grow = L > 2048 ? 2048 : L;
      gld16(w_rh + ((size_t)(b * 2049 + grow) << 10) + (h << 6) + ((s ^ (slot & 7)) << 3),
            &wbc[((slot << 3) | s) << 3]);
    }
  };
  auto stageWB2 = [&]() {
    for (int base = 0; base < 96; base += 32) {
      int r = (tid >> 3) + base, s = tid & 7;
      gld16(w_rh + ((size_t)(b * 2049 + r) << 10) + (h << 6) + ((s ^ (r & 7)) << 3),
            &wb2[((r << 3) | s) << 3]);
    }
  };
  const int kv2 = (tid & 15) << 1, d4 = ((tid >> 4) & 15) << 2, kw = tid & 15;
  auto loadV = [&](int kj, uint2& ra, uint2& rb) {
    const u16* vp = (const u16*)w_v + ((size_t)((b << 11) + kj + kv2) << 10) + (h << 6) + d4;
    ra = *reinterpret_cast<const uint2*>(vp);
    rb = *reinterpret_cast<const uint2*>(vp + 1024);
  };
  auto writeV = [&](int buf, uint2 ra, uint2 rb) {
    u32* vt32 = reinterpret_cast<u32*>(&vt[buf][0]);
    vt32[(d4 + 0) * 20 + kw] = (ra.x & 0xffffu) | (rb.x << 16);
    vt32[(d4 + 1) * 20 + kw] = (ra.x >> 16) | (rb.x & 0xffff0000u);
    vt32[(d4 + 2) * 20 + kw] = (ra.y & 0xffffu) | (rb.y << 16);
    vt32[(d4 + 3) * 20 + kw] = (ra.y >> 16) | (rb.y & 0xffff0000u);
  };
  const size_t qrowg = (size_t)((b << 10) + qi0 + myq);
  auto loadSP = [&](int kj, bf16x8& sA, bf16x8& sB, f32x4& pA, f32x4& pB) {
    const bf16* sp = seg_b + (qrowg * 2048 + kj + (l16 << 2)) * 2;
    sA = *reinterpret_cast<const bf16x8*>(sp);
    sB = *reinterpret_cast<const bf16x8*>(sp + 32);
    const float* pp = perm + qrowg * 2048 + kj + (l16 << 2);
    pA = *reinterpret_cast<const f32x4*>(pp);
    pB = *reinterpret_cast<const f32x4*>(pp + 16);
  };

  stageK(0, 0);
  stageWB(961 - qi0, 96, 7);
  uint2 ra0, rb0;
  loadV(0, ra0, rb0);
  bf16x8 segA_c, segB_c, segA_n = {}, segB_n = {};
  f32x4 pmA_c, pmB_c, pmA_n = {}, pmB_n = {};
  loadSP(0, segA_c, segB_c, pmA_c, pmB_c);

  const int dlo = l16 << 3;
  bf16x8 qcf0, qcf1, qrf0, qrf1, qrg0, qrg1;
  float qs0, qs1;
  {
    const bf16* qb  = w_q + ((qrowg) << 10) + (h << 6);
    const int rq1 = (qi0 + myq + 1 > 1023) ? 1023 : qi0 + myq + 1;
    const bf16* qb1 = w_q + (((size_t)(b << 10) + rq1) << 10) + (h << 6);
    f32x8 bc0 = *reinterpret_cast<const f32x8*>(bias_c + (h << 6) + dlo);
    f32x8 bc1 = *reinterpret_cast<const f32x8*>(bias_c + (h << 6) + 32 + dlo);
    f32x8 br0 = *reinterpret_cast<const f32x8*>(bias_r + (h << 6) + dlo);
    f32x8 br1 = *reinterpret_cast<const f32x8*>(bias_r + (h << 6) + 32 + dlo);
    bf16x8 q0 = *reinterpret_cast<const bf16x8*>(qb + dlo);
    bf16x8 q1 = *reinterpret_cast<const bf16x8*>(qb + 32 + dlo);
    bf16x8 p0 = *reinterpret_cast<const bf16x8*>(qb1 + dlo);
    bf16x8 p1 = *reinterpret_cast<const bf16x8*>(qb1 + 32 + dlo);
    f32x8 qf0 = __builtin_convertvector(q0, f32x8);
    f32x8 qf1 = __builtin_convertvector(q1, f32x8);
    qcf0 = __builtin_convertvector(qf0 + bc0, bf16x8);
    qcf1 = __builtin_convertvector(qf1 + bc1, bf16x8);
    qrf0 = __builtin_convertvector(qf0 + br0, bf16x8);
    qrf1 = __builtin_convertvector(qf1 + br1, bf16x8);
    qrg0 = __builtin_convertvector(__builtin_convertvector(p0, f32x8) + br0, bf16x8);
    qrg1 = __builtin_convertvector(__builtin_convertvector(p1, f32x8) + br1, bf16x8);
    f32x8 bs0 = *reinterpret_cast<const f32x8*>(bias_s + (h << 6) + dlo);
    f32x8 bs1 = *reinterpret_cast<const f32x8*>(bias_s + (h << 6) + 32 + dlo);
    f32x8 e00 = *reinterpret_cast<const f32x8*>(seg_embed + (h << 6) + dlo);
    f32x8 e01 = *reinterpret_cast<const f32x8*>(seg_embed + (h << 6) + 32 + dlo);
    f32x8 e10 = *reinterpret_cast<const f32x8*>(seg_embed + 1024 + (h << 6) + dlo);
    f32x8 e11 = *reinterpret_cast<const f32x8*>(seg_embed + 1024 + (h << 6) + 32 + dlo);
    f32x8 qa = qf0 + bs0, qb2 = qf1 + bs1;
    float t0 = 0.f, t1 = 0.f;
#pragma unroll
    for (int j = 0; j < 8; ++j) {
      t0 = fmaf(qa[j], e00[j], fmaf(qb2[j], e01[j], t0));
      t1 = fmaf(qa[j], e10[j], fmaf(qb2[j], e11[j], t1));
    }
    t0 += __shfl_xor(t0, 16); t0 += __shfl_xor(t0, 32);
    t1 += __shfl_xor(t1, 16); t1 += __shfl_xor(t1, 32);
    qs0 = t0; qs1 = t1;
  }

  writeV(0, ra0, rb0);
  __syncthreads();

  float mrow = -1e30f, lrow = 0.f;
  f32x4 o[4] = {};
  const float SCL = 0.125f * 1.44269504f;
  int cur = 0;
  uint2 ra_n = {}, rb_n = {};

  for (int t = 0; t < 64; ++t) {
    const int kj = t << 5;
    const int rel0 = kj - qi0;
    const bool strad = (rel0 == 1024) | (rel0 == 1056);
    const bool mainB = (rel0 >= 1088);
    const int nxt = cur ^ 1;

    if (t < 63) {
      const int kjn = kj + 32, rel0n = rel0 + 32;
      stageK(nxt, kjn);
      if (rel0n == 1024) stageWB2();
      if (rel0n == 1120)      stageWB(32, 96, 0);
      else if (rel0n != 1088) {
        if (rel0n <= 1056) stageWB(rel0n + 1025, 32, 7);
        else               stageWB(rel0n - 1024, 32, 0);
      }
      loadV(kjn, ra_n, rb_n);
      loadSP(kjn, segA_n, segB_n, pmA_n, pmB_n);
    }

    // context scores (swapped): D[k'][q=lc]
    f32x4 s0 = {0.f, 0.f, 0.f, 0.f}, s1 = {0.f, 0.f, 0.f, 0.f};
    {
      const bf16* ktc = kt[cur];
      bf16x8 a0 = *reinterpret_cast<const bf16x8*>(&ktc[SWZ(lc, l16) << 3]);
      bf16x8 a1 = *reinterpret_cast<const bf16x8*>(&ktc[SWZ(lc, l16 + 4) << 3]);
      bf16x8 a2 = *reinterpret_cast<const bf16x8*>(&ktc[SWZ(16 + lc, l16) << 3]);
      bf16x8 a3 = *reinterpret_cast<const bf16x8*>(&ktc[SWZ(16 + lc, l16 + 4) << 3]);
      s0 = mfma16(a0, qcf0, s0); s0 = mfma16(a1, qcf1, s0);
      s1 = mfma16(a2, qcf0, s1); s1 = mfma16(a3, qcf1, s1);
    }

    // relative term via ART[bandcol][q] + diagonal gather
    float relv[8];
    {
      const bf16x8 ar0 = mainB ? qrg0 : qrf0;
      const bf16x8 ar1 = mainB ? qrg1 : qrf1;
      const bool useWb2 = (rel0 == 1088);
      int sbase;
      if (!mainB)       sbase = (rel0 + 1016 - w16) & 127;
      else if (useWb2)  sbase = 48 - w16;
      else              sbase = (rel0 - 1040 - w16) & 127;
      const bf16* wbp = useWb2 ? wb2 : wbc;
#pragma unroll
      for (int bg = 0; bg < 3; ++bg) {
        int prow = sbase + (bg << 4) + lc;
        if (!useWb2) prow &= 127;
        bf16x8 w0 = *reinterpret_cast<const bf16x8*>(&wbp[SWZ(prow, l16) << 3]);
        bf16x8 w1 = *reinterpret_cast<const bf16x8*>(&wbp[SWZ(prow, l16 + 4) << 3]);
        f32x4 a_ = {0.f, 0.f, 0.f, 0.f};
        a_ = mfma16(ar0, w0, a_); a_ = mfma16(ar1, w1, a_);
        *reinterpret_cast<f32x4*>(&ART[w * 960 + ((bg << 4) + lc) * 20 + (l16 << 2)]) = a_;
      }
#pragma unroll
      for (int jj = 0; jj < 4; ++jj) {
        relv[jj]     = ART[w * 960 + (15 + (l16 << 2) + jj - lc) * 20 + lc];
        relv[4 + jj] = ART[w * 960 + (31 + (l16 << 2) + jj - lc) * 20 + lc];
      }
      if (strad) {
#pragma unroll
        for (int bg = 0; bg < 3; ++bg) {
          int srow = rel0 - 1040 - w16 + (bg << 4) + lc;
          srow = srow < 0 ? 0 : (srow > 95 ? 95 : srow);
          bf16x8 w0 = *reinterpret_cast<const bf16x8*>(&wb2[SWZ(srow, l16) << 3]);
          bf16x8 w1 = *reinterpret_cast<const bf16x8*>(&wb2[SWZ(srow, l16 + 4) << 3]);
          f32x4 a_ = {0.f, 0.f, 0.f, 0.f};
          a_ = mfma16(qrg0, w0, a_); a_ = mfma16(qrg1, w1, a_);
          *reinterpret_cast<f32x4*>(&ART[w * 960 + ((bg << 4) + lc) * 20 + (l16 << 2)]) = a_;
        }
#pragma unroll
        for (int jj = 0; jj < 4; ++jj) {
          const int jA = (l16 << 2) + jj, jB = 16 + jA;
          float rbA = ART[w * 960 + (15 + jA - lc) * 20 + lc];
          float rbB = ART[w * 960 + (15 + jB - lc) * 20 + lc];
          if (rel0 + jA - myq >= 1025) relv[jj] = rbA;
          if (rel0 + jB - myq >= 1025) relv[4 + jj] = rbB;
        }
      }
    }

    // in-register online softmax
    {
      f32x8 sgA = __builtin_convertvector(segA_c, f32x8);
      f32x8 sgB = __builtin_convertvector(segB_c, f32x8);
      float sv[8];
#pragma unroll
      for (int jj = 0; jj < 4; ++jj) {
        sv[jj]     = (s0[jj] + relv[jj]     + sgA[2 * jj] * qs0 + sgA[2 * jj + 1] * qs1) * SCL;
        sv[4 + jj] = (s1[jj] + relv[4 + jj] + sgB[2 * jj] * qs0 + sgB[2 * jj + 1] * qs1) * SCL;
      }
      float tm = sv[0];
#pragma unroll
      for (int jj = 1; jj < 8; ++jj) tm = fmaxf(tm, sv[jj]);
      tm = fmaxf(tm, __shfl_xor(tm, 16));
      tm = fmaxf(tm, __shfl_xor(tm, 32));
      const float mn2 = fmaxf(mrow, tm);
      const float facr = exp2f(mrow - mn2);
      float e[8], rs = 0.f;
#pragma unroll
      for (int jj = 0; jj < 4; ++jj) {
        e[jj]     = exp2f(sv[jj] - mn2) * pmA_c[jj];
        e[4 + jj] = exp2f(sv[4 + jj] - mn2) * pmB_c[jj];
        rs += e[jj] + e[4 + jj];
      }
      rs += __shfl_xor(rs, 16);
      rs += __shfl_xor(rs, 32);
      mrow = mn2;
      lrow = lrow * facr + rs;
      bf16x4 pa, pb;
#pragma unroll
      for (int jj = 0; jj < 4; ++jj) { pa[jj] = (bf16)e[jj]; pb[jj] = (bf16)e[4 + jj]; }
      *reinterpret_cast<bf16x4*>(&pl[myq * 40 + (l16 << 2)]) = pa;
      *reinterpret_cast<bf16x4*>(&pl[myq * 40 + 16 + (l16 << 2)]) = pb;
      if (l16 == 0) facw[myq] = facr;
    }

    // PV
    {
      float fr[4];
#pragma unroll
      for (int r = 0; r < 4; ++r) fr[r] = facw[w16 + (l16 << 2) + r];
#pragma unroll
      for (int n = 0; n < 4; ++n)
#pragma unroll
        for (int r = 0; r < 4; ++r) o[n][r] *= fr[r];
      bf16x8 ap = *reinterpret_cast<const bf16x8*>(&pl[(w16 + lc) * 40 + (l16 << 3)]);
      bf16x8 bv0 = *reinterpret_cast<const bf16x8*>(&vt[cur][(lc) * 40 + (l16 << 3)]);
      bf16x8 bv1 = *reinterpret_cast<const bf16x8*>(&vt[cur][(16 + lc) * 40 + (l16 << 3)]);
      bf16x8 bv2 = *reinterpret_cast<const bf16x8*>(&vt[cur][(32 + lc) * 40 + (l16 << 3)]);
      bf16x8 bv3 = *reinterpret_cast<const bf16x8*>(&vt[cur][(48 + lc) * 40 + (l16 << 3)]);
      o[0] = mfma16(ap, bv0, o[0]);
      o[1] = mfma16(ap, bv1, o[1]);
      o[2] = mfma16(ap, bv2, o[2]);
      o[3] = mfma16(ap, bv3, o[3]);
    }

    if (t < 63) {
      writeV(nxt, ra_n, rb_n);
      segA_c = segA_n; segB_c = segB_n; pmA_c = pmA_n; pmB_c = pmB_n;
    }
    __syncthreads();
    cur = nxt;
  }

  // epilogue: normalize, hi|lo concat store (row stride 2048)
  if (l16 == 0) lroww[myq] = lrow;
  {
    float inv[4];
#pragma unroll
    for (int r = 0; r < 4; ++r)
      inv[r] = 1.f / (lroww[w16 + (l16 << 2) + r] + 1e-7f);
#pragma unroll
    for (int n = 0; n < 4; ++n) {
#pragma unroll
      for (int r = 0; r < 4; ++r) {
        const int row = qi0 + w16 + (l16 << 2) + r;
        const float v = o[n][r] * inv[r];
        const bf16 hi = (bf16)v;
        const float lof = v - (float)hi;
        const size_t off = (((size_t)(b << 10) + row) << 11) + (h << 6) + (n << 4) + lc;
        a_cat[off] = hi;
        a_cat[off + 1024] = (bf16)lof;
      }
    }
  }
}

// ---------------------------------------------------------------------------
extern "C" void kernel_launch(void* const* d_in, const int* in_sizes, int n_in,
                              void* d_out, int out_size, void* d_ws, size_t ws_size,
                              hipStream_t stream) {
  (void)in_sizes; (void)n_in; (void)out_size; (void)ws_size;
  const float* inputs    = (const float*)d_in[0];
  const float* content   = (const float*)d_in[1];
  const float* memories  = (const float*)d_in[2];
  const float* relatives = (const float*)d_in[3];
  const float* seg_mat   = (const float*)d_in[4];
  const float* seg_embed = (const float*)d_in[5];
  const float* bias_c    = (const float*)d_in[6];
  const float* bias_r    = (const float*)d_in[7];
  const float* bias_s    = (const float*)d_in[8];
  const float* perm      = (const float*)d_in[9];
  const float* kern      = (const float*)d_in[10];
  float* out = (float*)d_out;

  char* ws = (char*)d_ws;
  bf16*  seg_b  = (bf16*)(ws);                 // [0, 16.78 MB)  (live through attn)
  bf16*  kT     = (bf16*)(ws + 21233664);      // [21.23, 31.72 MB)
  bf16*  w_q    = (bf16*)(ws + 31719424);
  bf16*  w_k    = (bf16*)(ws + 35913728);
  bf16*  w_v    = (bf16*)(ws + 44302336);
  bf16*  w_rh   = (bf16*)(ws + 52690944);      // ends 61,083,648
  // aliases of dead regions:
  bf16*  a_cat  = (bf16*)(ws + 21233664);      // over kT rows 0..4095 (dead after proj)
  bf16*  kTo    = (bf16*)(ws + 29622272);      // kT rows 4096..5119 (k_o^T)

  dim3 blk(256);
  prep_all<<<5376, blk, 0, stream>>>(kern, seg_mat, kT, seg_b);
  proj_fused<<<904, blk, 0, stream>>>(inputs, memories, content, relatives, kT,
                                      w_q, w_k, w_v, w_rh);
  attn_mfma<<<512, blk, 0, stream>>>(w_q, w_k, w_v, w_rh, seg_b, perm,
                                     bias_c, bias_r, bias_s, seg_embed, a_cat);
  out_proj<<<256, blk, 0, stream>>>(a_cat, kTo, out);
}

// Round 15
// 244.698 us; speedup vs baseline: 1.0272x; 1.0272x over previous
//
#include <hip/hip_runtime.h>

typedef __bf16 bf16;
typedef unsigned short u16;
typedef unsigned int u32;
typedef __attribute__((ext_vector_type(8))) __bf16 bf16x8;
typedef __attribute__((ext_vector_type(4))) __bf16 bf16x4;
typedef __attribute__((ext_vector_type(4))) float f32x4;
typedef __attribute__((ext_vector_type(8))) float f32x8;

// slot index (16B units) for 8-seg rows (64 bf16/row), XOR-swizzled
#define SWZ(r, s) (((r) << 3) + ((s) ^ ((r) & 7)))
// slot index for 4-seg rows (32 bf16/row), XOR-swizzled
#define GSW(r, s) (((r) << 2) + ((s) ^ (((r) >> 1) & 3)))

__device__ __forceinline__ f32x4 mfma16(bf16x8 a, bf16x8 b, f32x4 c) {
  return __builtin_amdgcn_mfma_f32_16x16x32_bf16(a, b, c, 0, 0, 0);
}
__device__ __forceinline__ void gld16(const void* g, void* l) {
  __builtin_amdgcn_global_load_lds((const __attribute__((address_space(1))) void*)g,
                                   (__attribute__((address_space(3))) void*)l, 16, 0, 0);
}

// ---------------------------------------------------------------------------
// prep_all: kT transpose (blocks [0,1280)) + seg_mat->bf16 (blocks [1280,5376))
// ---------------------------------------------------------------------------
__global__ __launch_bounds__(256) void prep_all(
    const float* __restrict__ K, const float* __restrict__ seg_mat,
    bf16* __restrict__ KT, bf16* __restrict__ seg_b) {
  __shared__ float t[64][68];
  const int bid = blockIdx.x, tid = threadIdx.x;
  if (bid < 1280) {
    const int n0 = (bid % 80) << 6, k0 = (bid / 80) << 6;
    for (int idx = tid; idx < 1024; idx += 256) {
      int rr = idx >> 4, c4 = (idx & 15) << 2;
      f32x4 v = *reinterpret_cast<const f32x4*>(K + (size_t)(k0 + rr) * 5120 + n0 + c4);
      t[rr][c4] = v.x; t[rr][c4 + 1] = v.y; t[rr][c4 + 2] = v.z; t[rr][c4 + 3] = v.w;
    }
    __syncthreads();
    for (int idx = tid; idx < 1024; idx += 256) {
      int rr = idx >> 4, c4 = (idx & 15) << 2;
      bf16x4 o = { (bf16)t[c4][rr], (bf16)t[c4 + 1][rr], (bf16)t[c4 + 2][rr], (bf16)t[c4 + 3][rr] };
      *reinterpret_cast<bf16x4*>(KT + (size_t)(n0 + rr) * 1024 + k0 + c4) = o;
    }
  } else {
    size_t i = ((size_t)(bid - 1280) * 256 + tid) * 8;
    f32x8 v = *reinterpret_cast<const f32x8*>(seg_mat + i);
    *reinterpret_cast<bf16x8*>(seg_b + i) = __builtin_convertvector(v, bf16x8);
  }
}

// ---------------------------------------------------------------------------
// GEMM with f32 A-source, converted to bf16 during staging (reg->cvt->LDS).
// AMODE 0: A1 + row*1024. AMODE 1: full (mem/cont split). AMODE 2: clamp 4097.
// Output bf16; col < splitN -> C0 else C1.
// ---------------------------------------------------------------------------
template<int MT, int AMODE>
__device__ __forceinline__ void gemm_f32a(
    const float* __restrict__ A1, const float* __restrict__ A2,
    const bf16* __restrict__ BT, bf16* __restrict__ C0, bf16* __restrict__ C1,
    int m0, int n0, int Mrows, int splitN, bf16* As, bf16* Bs, int tid) {
  const int l = tid & 63, w = tid >> 6;
  const int wn = (w & 1) << 6;
  const int wm = (w >> 1) * (MT / 2);
  constexpr int MFR = MT / 32;
  const int lc = l & 15, l16 = l >> 4;
  f32x4 acc[MFR][4] = {};
  const int r0 = tid >> 2;
  const int sq = tid & 3;
  const int g0 = (sq ^ ((r0 >> 1) & 3)) << 3;   // B pre-swizzled global seg

  auto arow = [&](int row) -> const float* {
    if (AMODE == 0) return A1 + ((size_t)row << 10);
    if (AMODE == 1) {
      int b = row >> 11, rr = row & 2047;
      return (rr < 1024) ? (A1 + (((size_t)(b << 10) + rr) << 10))
                         : (A2 + (((size_t)(b << 10) + (rr - 1024)) << 10));
    }
    int rr = row > 4097 ? 4097 : row;           // relatives has exactly 4098 rows
    return A1 + ((size_t)rr << 10);
  };
  const float* ap0 = arow(m0 + r0);
  const float* ap1 = (MT == 128) ? arow(m0 + r0 + 64) : nullptr;
  // LDS slot (bf16 elems) matching the GSW read: slot r*4+(s^((r>>1)&3)) holds seg s
  const int aslot0 = ((r0 << 2) + (sq ^ ((r0 >> 1) & 3))) << 3;
  const int aslot1 = (((r0 + 64) << 2) + (sq ^ ((r0 >> 1) & 3))) << 3;

  for (int k0 = 0; k0 < 1024; k0 += 32) {
    // issue f32 A loads early (hidden under previous MFMA phase)
    f32x8 a0 = *reinterpret_cast<const f32x8*>(ap0 + k0 + (sq << 3));
    f32x8 a1v = {};
    if (MT == 128) a1v = *reinterpret_cast<const f32x8*>(ap1 + k0 + (sq << 3));
    __syncthreads();   // (a) previous tile consumed
    *reinterpret_cast<bf16x8*>(&As[aslot0]) = __builtin_convertvector(a0, bf16x8);
    if (MT == 128)
      *reinterpret_cast<bf16x8*>(&As[aslot1]) = __builtin_convertvector(a1v, bf16x8);
    gld16(BT + (size_t)(n0 + r0) * 1024 + k0 + g0, &Bs[tid << 3]);
    gld16(BT + (size_t)(n0 + r0 + 64) * 1024 + k0 + g0, &Bs[(tid + 256) << 3]);
    __syncthreads();   // (b) tile ready
    bf16x8 af[MFR], bfv[4];
#pragma unroll
    for (int m = 0; m < MFR; ++m)
      af[m] = *reinterpret_cast<const bf16x8*>(&As[GSW(wm + (m << 4) + lc, l16) << 3]);
#pragma unroll
    for (int n = 0; n < 4; ++n)
      bfv[n] = *reinterpret_cast<const bf16x8*>(&Bs[GSW(wn + (n << 4) + lc, l16) << 3]);
#pragma unroll
    for (int m = 0; m < MFR; ++m)
#pragma unroll
      for (int n = 0; n < 4; ++n)
        acc[m][n] = mfma16(af[m], bfv[n], acc[m][n]);
  }
#pragma unroll
  for (int m = 0; m < MFR; ++m) {
    const int rbase = m0 + wm + (m << 4) + (l16 << 2);
#pragma unroll
    for (int n = 0; n < 4; ++n) {
      const int col = n0 + wn + (n << 4) + lc;
      const int cc = (col < splitN) ? col : (col - splitN);
      bf16* Cv = (col < splitN) ? C0 : C1;
#pragma unroll
      for (int r = 0; r < 4; ++r) {
        const int row = rbase + r;
        if (row < Mrows) Cv[((size_t)row << 10) + cc] = (bf16)acc[m][n][r];
      }
    }
  }
}

// all three projection GEMMs in one launch (1288 blocks), A from f32 inputs
__global__ __launch_bounds__(256) void proj_fused(
    const float* __restrict__ inputs, const float* __restrict__ mem,
    const float* __restrict__ cont, const float* __restrict__ rel,
    const bf16* __restrict__ kT, bf16* __restrict__ w_q, bf16* __restrict__ w_k,
    bf16* __restrict__ w_v, bf16* __restrict__ w_rh) {
  __shared__ bf16 As[4096];
  __shared__ bf16 Bs[4096];
  const int bid = blockIdx.x, tid = threadIdx.x;
  if (bid < 256) {          // w_q: 32m(64) x 8n
    gemm_f32a<64, 0>(inputs, nullptr, kT, w_q, w_q,
                     (bid >> 3) << 6, (bid & 7) << 7, 2048, 1 << 30, As, Bs, tid);
  } else if (bid < 768) {   // w_kv: 32m(128) x 16n
    const int r = bid - 256;
    gemm_f32a<128, 1>(mem, cont, kT + (1 << 20), w_k, w_v,
                      (r >> 4) << 7, (r & 15) << 7, 4096, 1024, As, Bs, tid);
  } else {                  // w_r: 65m(64) x 8n
    const int r = bid - 768;
    gemm_f32a<64, 2>(rel, nullptr, kT + 3 * (1 << 20), w_rh, w_rh,
                     (r >> 3) << 6, (r & 7) << 7, 4098, 1 << 30, As, Bs, tid);
  }
}

// ---------------------------------------------------------------------------
// out_proj: bf16-A GEMM (a_cat hi|lo, K=2048 with B k-wrap), f32 out
// ---------------------------------------------------------------------------
__global__ __launch_bounds__(256) void out_proj(
    const bf16* __restrict__ a_cat, const bf16* __restrict__ kTo,
    float* __restrict__ out) {
  __shared__ bf16 As[4096];
  __shared__ bf16 Bs[4096];
  const int bid = blockIdx.x, tid = threadIdx.x;
  const int m0 = (bid >> 3) << 6, n0 = (bid & 7) << 7;
  const int l = tid & 63, w = tid >> 6;
  const int wn = (w & 1) << 6;
  const int wm = (w >> 1) << 5;
  const int lc = l & 15, l16 = l >> 4;
  f32x4 acc[2][4] = {};
  const int r0 = tid >> 2;
  const int sq = tid & 3;
  const int g0 = (sq ^ ((r0 >> 1) & 3)) << 3;

  for (int k0 = 0; k0 < 2048; k0 += 32) {
    const int kk = k0 & 1023;
    __syncthreads();
    gld16(a_cat + (size_t)(m0 + r0) * 2048 + k0 + g0, &As[tid << 3]);
    gld16(kTo + (size_t)(n0 + r0) * 1024 + kk + g0, &Bs[tid << 3]);
    gld16(kTo + (size_t)(n0 + r0 + 64) * 1024 + kk + g0, &Bs[(tid + 256) << 3]);
    __syncthreads();
    bf16x8 af[2], bfv[4];
#pragma unroll
    for (int m = 0; m < 2; ++m)
      af[m] = *reinterpret_cast<const bf16x8*>(&As[GSW(wm + (m << 4) + lc, l16) << 3]);
#pragma unroll
    for (int n = 0; n < 4; ++n)
      bfv[n] = *reinterpret_cast<const bf16x8*>(&Bs[GSW(wn + (n << 4) + lc, l16) << 3]);
#pragma unroll
    for (int m = 0; m < 2; ++m)
#pragma unroll
      for (int n = 0; n < 4; ++n)
        acc[m][n] = mfma16(af[m], bfv[n], acc[m][n]);
  }
#pragma unroll
  for (int m = 0; m < 2; ++m) {
    const int rbase = m0 + wm + (m << 4) + (l16 << 2);
#pragma unroll
    for (int n = 0; n < 4; ++n) {
      const int col = n0 + wn + (n << 4) + lc;
#pragma unroll
      for (int r = 0; r < 4; ++r)
        out[((size_t)(rbase + r) << 10) + col] = acc[m][n][r];
    }
  }
}

// ---------------------------------------------------------------------------
// fused attention: round-12 proven structure (frozen). qs in prologue.
// NO setprio, NO defer branch.
// rel shift: diff=j_g-i_g; diff<=1024 -> q_r[i].w_r[diff+1024]
//            diff>=1025 -> q_r[i+1].w_r[diff-1025]
// ---------------------------------------------------------------------------
__global__ __launch_bounds__(256) void attn_mfma(
    const bf16* __restrict__ w_q, const bf16* __restrict__ w_k,
    const bf16* __restrict__ w_v, const bf16* __restrict__ w_rh,
    const bf16* __restrict__ seg_b, const float* __restrict__ perm,
    const float* __restrict__ bias_c, const float* __restrict__ bias_r,
    const float* __restrict__ bias_s, const float* __restrict__ seg_embed,
    bf16* __restrict__ a_cat) {
  const int id = blockIdx.x;
  const int h  = (id >> 3) & 15;
  const int cg = (id & 7) | ((id >> 7) << 3);
  const int qt = cg & 15, b = cg >> 4;
  const int qi0 = qt << 6;
  const int tid = threadIdx.x;
  const int w = tid >> 6, l = tid & 63;
  const int lc = l & 15, l16 = l >> 4;
  const int w16 = w << 4;
  const int myq = w16 + lc;

  __shared__ bf16 kt[2][2048];
  __shared__ u16  vt[2][2560];
  __shared__ bf16 wbc[8192];
  __shared__ bf16 wb2[6144];      // w_r rows 0..95
  __shared__ u16  pl[2560];
  __shared__ float ART[4 * 960];
  __shared__ float facw[64], lroww[64];

  auto stageK = [&](int buf, int kj) {
    int r = tid >> 3, s = tid & 7;
    gld16(w_k + ((size_t)((b << 11) + kj + r) << 10) + (h << 6) + ((s ^ (r & 7)) << 3),
          &kt[buf][tid << 3]);
  };
  auto stageWB = [&](int L0, int nrows, int OFF) {
    for (int base = 0; base < nrows; base += 32) {
      int r = (tid >> 3) + base, s = tid & 7;
      int L = L0 + r;
      int slot = (L + OFF) & 127;
      int grow = L > 2048 ? 2048 : L;
      gld16(w_rh + ((size_t)(b * 2049 + grow) << 10) + (h << 6) + ((s ^ (slot & 7)) << 3),
            &wbc[((slot << 3) | s) << 3]);
    }
  };
  auto stageWB2 = [&]() {
    for (int base = 0; base < 96; base += 32) {
      int r = (tid >> 3) + base, s = tid & 7;
      gld16(w_rh + ((size_t)(b * 2049 + r) << 10) + (h << 6) + ((s ^ (r & 7)) << 3),
            &wb2[((r << 3) | s) << 3]);
    }
  };
  const int kv2 = (tid & 15) << 1, d4 = ((tid >> 4) & 15) << 2, kw = tid & 15;
  auto loadV = [&](int kj, uint2& ra, uint2& rb) {
    const u16* vp = (const u16*)w_v + ((size_t)((b << 11) + kj + kv2) << 10) + (h << 6) + d4;
    ra = *reinterpret_cast<const uint2*>(vp);
    rb = *reinterpret_cast<const uint2*>(vp + 1024);
  };
  auto writeV = [&](int buf, uint2 ra, uint2 rb) {
    u32* vt32 = reinterpret_cast<u32*>(&vt[buf][0]);
    vt32[(d4 + 0) * 20 + kw] = (ra.x & 0xffffu) | (rb.x << 16);
    vt32[(d4 + 1) * 20 + kw] = (ra.x >> 16) | (rb.x & 0xffff0000u);
    vt32[(d4 + 2) * 20 + kw] = (ra.y & 0xffffu) | (rb.y << 16);
    vt32[(d4 + 3) * 20 + kw] = (ra.y >> 16) | (rb.y & 0xffff0000u);
  };
  const size_t qrowg = (size_t)((b << 10) + qi0 + myq);
  auto loadSP = [&](int kj, bf16x8& sA, bf16x8& sB, f32x4& pA, f32x4& pB) {
    const bf16* sp = seg_b + (qrowg * 2048 + kj + (l16 << 2)) * 2;
    sA = *reinterpret_cast<const bf16x8*>(sp);
    sB = *reinterpret_cast<const bf16x8*>(sp + 32);
    const float* pp = perm + qrowg * 2048 + kj + (l16 << 2);
    pA = *reinterpret_cast<const f32x4*>(pp);
    pB = *reinterpret_cast<const f32x4*>(pp + 16);
  };

  stageK(0, 0);
  stageWB(961 - qi0, 96, 7);
  uint2 ra0, rb0;
  loadV(0, ra0, rb0);
  bf16x8 segA_c, segB_c, segA_n = {}, segB_n = {};
  f32x4 pmA_c, pmB_c, pmA_n = {}, pmB_n = {};
  loadSP(0, segA_c, segB_c, pmA_c, pmB_c);

  const int dlo = l16 << 3;
  bf16x8 qcf0, qcf1, qrf0, qrf1, qrg0, qrg1;
  float qs0, qs1;
  {
    const bf16* qb  = w_q + ((qrowg) << 10) + (h << 6);
    const int rq1 = (qi0 + myq + 1 > 1023) ? 1023 : qi0 + myq + 1;
    const bf16* qb1 = w_q + (((size_t)(b << 10) + rq1) << 10) + (h << 6);
    f32x8 bc0 = *reinterpret_cast<const f32x8*>(bias_c + (h << 6) + dlo);
    f32x8 bc1 = *reinterpret_cast<const f32x8*>(bias_c + (h << 6) + 32 + dlo);
    f32x8 br0 = *reinterpret_cast<const f32x8*>(bias_r + (h << 6) + dlo);
    f32x8 br1 = *reinterpret_cast<const f32x8*>(bias_r + (h << 6) + 32 + dlo);
    bf16x8 q0 = *reinterpret_cast<const bf16x8*>(qb + dlo);
    bf16x8 q1 = *reinterpret_cast<const bf16x8*>(qb + 32 + dlo);
    bf16x8 p0 = *reinterpret_cast<const bf16x8*>(qb1 + dlo);
    bf16x8 p1 = *reinterpret_cast<const bf16x8*>(qb1 + 32 + dlo);
    f32x8 qf0 = __builtin_convertvector(q0, f32x8);
    f32x8 qf1 = __builtin_convertvector(q1, f32x8);
    qcf0 = __builtin_convertvector(qf0 + bc0, bf16x8);
    qcf1 = __builtin_convertvector(qf1 + bc1, bf16x8);
    qrf0 = __builtin_convertvector(qf0 + br0, bf16x8);
    qrf1 = __builtin_convertvector(qf1 + br1, bf16x8);
    qrg0 = __builtin_convertvector(__builtin_convertvector(p0, f32x8) + br0, bf16x8);
    qrg1 = __builtin_convertvector(__builtin_convertvector(p1, f32x8) + br1, bf16x8);
    // qs in-register: (w_q+bias_s).seg_embed over this lane's 16 dims,
    // then 4-lane shfl_xor reduce (lanes sharing lc cover all 64 dims).
    f32x8 bs0 = *reinterpret_cast<const f32x8*>(bias_s + (h << 6) + dlo);
    f32x8 bs1 = *reinterpret_cast<const f32x8*>(bias_s + (h << 6) + 32 + dlo);
    f32x8 e00 = *reinterpret_cast<const f32x8*>(seg_embed + (h << 6) + dlo);
    f32x8 e01 = *reinterpret_cast<const f32x8*>(seg_embed + (h << 6) + 32 + dlo);
    f32x8 e10 = *reinterpret_cast<const f32x8*>(seg_embed + 1024 + (h << 6) + dlo);
    f32x8 e11 = *reinterpret_cast<const f32x8*>(seg_embed + 1024 + (h << 6) + 32 + dlo);
    f32x8 qa = qf0 + bs0, qb2 = qf1 + bs1;
    float t0 = 0.f, t1 = 0.f;
#pragma unroll
    for (int j = 0; j < 8; ++j) {
      t0 = fmaf(qa[j], e00[j], fmaf(qb2[j], e01[j], t0));
      t1 = fmaf(qa[j], e10[j], fmaf(qb2[j], e11[j], t1));
    }
    t0 += __shfl_xor(t0, 16); t0 += __shfl_xor(t0, 32);
    t1 += __shfl_xor(t1, 16); t1 += __shfl_xor(t1, 32);
    qs0 = t0; qs1 = t1;
  }

  writeV(0, ra0, rb0);
  __syncthreads();

  float mrow = -1e30f, lrow = 0.f;
  f32x4 o[4] = {};
  const float SCL = 0.125f * 1.44269504f;
  int cur = 0;
  uint2 ra_n = {}, rb_n = {};

  for (int t = 0; t < 64; ++t) {
    const int kj = t << 5;
    const int rel0 = kj - qi0;
    const bool strad = (rel0 == 1024) | (rel0 == 1056);
    const bool mainB = (rel0 >= 1088);
    const int nxt = cur ^ 1;

    if (t < 63) {
      const int kjn = kj + 32, rel0n = rel0 + 32;
      stageK(nxt, kjn);
      if (rel0n == 1024) stageWB2();
      if (rel0n == 1120)      stageWB(32, 96, 0);
      else if (rel0n != 1088) {
        if (rel0n <= 1056) stageWB(rel0n + 1025, 32, 7);
        else               stageWB(rel0n - 1024, 32, 0);
      }
      loadV(kjn, ra_n, rb_n);
      loadSP(kjn, segA_n, segB_n, pmA_n, pmB_n);
    }

    // context scores (swapped): D[k'][q=lc]
    f32x4 s0 = {0.f, 0.f, 0.f, 0.f}, s1 = {0.f, 0.f, 0.f, 0.f};
    {
      const bf16* ktc = kt[cur];
      bf16x8 a0 = *reinterpret_cast<const bf16x8*>(&ktc[SWZ(lc, l16) << 3]);
      bf16x8 a1 = *reinterpret_cast<const bf16x8*>(&ktc[SWZ(lc, l16 + 4) << 3]);
      bf16x8 a2 = *reinterpret_cast<const bf16x8*>(&ktc[SWZ(16 + lc, l16) << 3]);
      bf16x8 a3 = *reinterpret_cast<const bf16x8*>(&ktc[SWZ(16 + lc, l16 + 4) << 3]);
      s0 = mfma16(a0, qcf0, s0); s0 = mfma16(a1, qcf1, s0);
      s1 = mfma16(a2, qcf0, s1); s1 = mfma16(a3, qcf1, s1);
    }

    // relative term via ART[bandcol][q] + diagonal gather
    float relv[8];
    {
      const bf16x8 ar0 = mainB ? qrg0 : qrf0;
      const bf16x8 ar1 = mainB ? qrg1 : qrf1;
      const bool useWb2 = (rel0 == 1088);
      int sbase;
      if (!mainB)       sbase = (rel0 + 1016 - w16) & 127;
      else if (useWb2)  sbase = 48 - w16;
      else              sbase = (rel0 - 1040 - w16) & 127;
      const bf16* wbp = useWb2 ? wb2 : wbc;
#pragma unroll
      for (int bg = 0; bg < 3; ++bg) {
        int prow = sbase + (bg << 4) + lc;
        if (!useWb2) prow &= 127;
        bf16x8 w0 = *reinterpret_cast<const bf16x8*>(&wbp[SWZ(prow, l16) << 3]);
        bf16x8 w1 = *reinterpret_cast<const bf16x8*>(&wbp[SWZ(prow, l16 + 4) << 3]);
        f32x4 a_ = {0.f, 0.f, 0.f, 0.f};
        a_ = mfma16(ar0, w0, a_); a_ = mfma16(ar1, w1, a_);
        *reinterpret_cast<f32x4*>(&ART[w * 960 + ((bg << 4) + lc) * 20 + (l16 << 2)]) = a_;
      }
#pragma unroll
      for (int jj = 0; jj < 4; ++jj) {
        relv[jj]     = ART[w * 960 + (15 + (l16 << 2) + jj - lc) * 20 + lc];
        relv[4 + jj] = ART[w * 960 + (31 + (l16 << 2) + jj - lc) * 20 + lc];
      }
      if (strad) {
#pragma unroll
        for (int bg = 0; bg < 3; ++bg) {
          int srow = rel0 - 1040 - w16 + (bg << 4) + lc;
          srow = srow < 0 ? 0 : (srow > 95 ? 95 : srow);
          bf16x8 w0 = *reinterpret_cast<const bf16x8*>(&wb2[SWZ(srow, l16) << 3]);
          bf16x8 w1 = *reinterpret_cast<const bf16x8*>(&wb2[SWZ(srow, l16 + 4) << 3]);
          f32x4 a_ = {0.f, 0.f, 0.f, 0.f};
          a_ = mfma16(qrg0, w0, a_); a_ = mfma16(qrg1, w1, a_);
          *reinterpret_cast<f32x4*>(&ART[w * 960 + ((bg << 4) + lc) * 20 + (l16 << 2)]) = a_;
        }
#pragma unroll
        for (int jj = 0; jj < 4; ++jj) {
          const int jA = (l16 << 2) + jj, jB = 16 + jA;
          float rbA = ART[w * 960 + (15 + jA - lc) * 20 + lc];
          float rbB = ART[w * 960 + (15 + jB - lc) * 20 + lc];
          if (rel0 + jA - myq >= 1025) relv[jj] = rbA;
          if (rel0 + jB - myq >= 1025) relv[4 + jj] = rbB;
        }
      }
    }

    // in-register online softmax
    {
      f32x8 sgA = __builtin_convertvector(segA_c, f32x8);
      f32x8 sgB = __builtin_convertvector(segB_c, f32x8);
      float sv[8];
#pragma unroll
      for (int jj = 0; jj < 4; ++jj) {
        sv[jj]     = (s0[jj] + relv[jj]     + sgA[2 * jj] * qs0 + sgA[2 * jj + 1] * qs1) * SCL;
        sv[4 + jj] = (s1[jj] + relv[4 + jj] + sgB[2 * jj] * qs0 + sgB[2 * jj + 1] * qs1) * SCL;
      }
      float tm = sv[0];
#pragma unroll
      for (int jj = 1; jj < 8; ++jj) tm = fmaxf(tm, sv[jj]);
      tm = fmaxf(tm, __shfl_xor(tm, 16));
      tm = fmaxf(tm, __shfl_xor(tm, 32));
      const float mn2 = fmaxf(mrow, tm);
      const float facr = exp2f(mrow - mn2);
      float e[8], rs = 0.f;
#pragma unroll
      for (int jj = 0; jj < 4; ++jj) {
        e[jj]     = exp2f(sv[jj] - mn2) * pmA_c[jj];
        e[4 + jj] = exp2f(sv[4 + jj] - mn2) * pmB_c[jj];
        rs += e[jj] + e[4 + jj];
      }
      rs += __shfl_xor(rs, 16);
      rs += __shfl_xor(rs, 32);
      mrow = mn2;
      lrow = lrow * facr + rs;
      bf16x4 pa, pb;
#pragma unroll
      for (int jj = 0; jj < 4; ++jj) { pa[jj] = (bf16)e[jj]; pb[jj] = (bf16)e[4 + jj]; }
      *reinterpret_cast<bf16x4*>(&pl[myq * 40 + (l16 << 2)]) = pa;
      *reinterpret_cast<bf16x4*>(&pl[myq * 40 + 16 + (l16 << 2)]) = pb;
      if (l16 == 0) facw[myq] = facr;
    }

    // PV
    {
      float fr[4];
#pragma unroll
      for (int r = 0; r < 4; ++r) fr[r] = facw[w16 + (l16 << 2) + r];
#pragma unroll
      for (int n = 0; n < 4; ++n)
#pragma unroll
        for (int r = 0; r < 4; ++r) o[n][r] *= fr[r];
      bf16x8 ap = *reinterpret_cast<const bf16x8*>(&pl[(w16 + lc) * 40 + (l16 << 3)]);
      bf16x8 bv0 = *reinterpret_cast<const bf16x8*>(&vt[cur][(lc) * 40 + (l16 << 3)]);
      bf16x8 bv1 = *reinterpret_cast<const bf16x8*>(&vt[cur][(16 + lc) * 40 + (l16 << 3)]);
      bf16x8 bv2 = *reinterpret_cast<const bf16x8*>(&vt[cur][(32 + lc) * 40 + (l16 << 3)]);
      bf16x8 bv3 = *reinterpret_cast<const bf16x8*>(&vt[cur][(48 + lc) * 40 + (l16 << 3)]);
      o[0] = mfma16(ap, bv0, o[0]);
      o[1] = mfma16(ap, bv1, o[1]);
      o[2] = mfma16(ap, bv2, o[2]);
      o[3] = mfma16(ap, bv3, o[3]);
    }

    if (t < 63) {
      writeV(nxt, ra_n, rb_n);
      segA_c = segA_n; segB_c = segB_n; pmA_c = pmA_n; pmB_c = pmB_n;
    }
    __syncthreads();
    cur = nxt;
  }

  // epilogue: normalize, hi|lo concat store (row stride 2048)
  if (l16 == 0) lroww[myq] = lrow;
  {
    float inv[4];
#pragma unroll
    for (int r = 0; r < 4; ++r)
      inv[r] = 1.f / (lroww[w16 + (l16 << 2) + r] + 1e-7f);
#pragma unroll
    for (int n = 0; n < 4; ++n) {
#pragma unroll
      for (int r = 0; r < 4; ++r) {
        const int row = qi0 + w16 + (l16 << 2) + r;
        const float v = o[n][r] * inv[r];
        const bf16 hi = (bf16)v;
        const float lof = v - (float)hi;
        const size_t off = (((size_t)(b << 10) + row) << 11) + (h << 6) + (n << 4) + lc;
        a_cat[off] = hi;
        a_cat[off + 1024] = (bf16)lof;
      }
    }
  }
}

// ---------------------------------------------------------------------------
extern "C" void kernel_launch(void* const* d_in, const int* in_sizes, int n_in,
                              void* d_out, int out_size, void* d_ws, size_t ws_size,
                              hipStream_t stream) {
  (void)in_sizes; (void)n_in; (void)out_size; (void)ws_size;
  const float* inputs    = (const float*)d_in[0];
  const float* content   = (const float*)d_in[1];
  const float* memories  = (const float*)d_in[2];
  const float* relatives = (const float*)d_in[3];
  const float* seg_mat   = (const float*)d_in[4];
  const float* seg_embed = (const float*)d_in[5];
  const float* bias_c    = (const float*)d_in[6];
  const float* bias_r    = (const float*)d_in[7];
  const float* bias_s    = (const float*)d_in[8];
  const float* perm      = (const float*)d_in[9];
  const float* kern      = (const float*)d_in[10];
  float* out = (float*)d_out;

  char* ws = (char*)d_ws;
  bf16*  seg_b  = (bf16*)(ws);                 // [0, 16.78 MB)  (live through attn)
  bf16*  kT     = (bf16*)(ws + 21233664);      // [21.23, 31.72 MB)
  bf16*  w_q    = (bf16*)(ws + 31719424);
  bf16*  w_k    = (bf16*)(ws + 35913728);
  bf16*  w_v    = (bf16*)(ws + 44302336);
  bf16*  w_rh   = (bf16*)(ws + 52690944);      // ends 61,083,648
  // aliases of dead regions:
  bf16*  a_cat  = (bf16*)(ws + 21233664);      // over kT rows 0..4095 (dead after proj)
  bf16*  kTo    = (bf16*)(ws + 29622272);      // kT rows 4096..5119 (k_o^T)

  dim3 blk(256);
  prep_all<<<5376, blk, 0, stream>>>(kern, seg_mat, kT, seg_b);
  proj_fused<<<1288, blk, 0, stream>>>(inputs, memories, content, relatives, kT,
                                       w_q, w_k, w_v, w_rh);
  attn_mfma<<<512, blk, 0, stream>>>(w_q, w_k, w_v, w_rh, seg_b, perm,
                                     bias_c, bias_r, bias_s, seg_embed, a_cat);
  out_proj<<<256, blk, 0, stream>>>(a_cat, kTo, out);
}